// Round 1
// baseline (440.888 us; speedup 1.0000x reference)
//
#include <hip/hip_runtime.h>
#include <hip/hip_bf16.h>

// MHA forward: B=4, S=2048, D=1024, H=16, DH=64. fp32 in/out, bf16 MFMA inside.

#define Bq 4
#define Sq 2048
#define Dq 1024
#define Hq 16
#define DHq 64

typedef __attribute__((ext_vector_type(8))) short short8;
typedef __attribute__((ext_vector_type(4))) float f32x4;
typedef __attribute__((ext_vector_type(4))) unsigned short ushort4v;

static __device__ __forceinline__ unsigned short f2bfu(float f) {
    union { __hip_bfloat16 h; unsigned short u; } cv;
    cv.h = __float2bfloat16(f);
    return cv.u;
}

// ---------------------------------------------------------------------------
// Kernel 1: QKV projections. Y = X @ W^T, scattered to [B,H,S,DH] bf16.
// Tile 128x128, BK=64, 4 waves (2x2), each wave 64x64 via 4x4 16x16x32 MFMAs.
// ---------------------------------------------------------------------------
__global__ __launch_bounds__(256) void qkv_gemm(
    const float* __restrict__ X,
    const float* __restrict__ Wq, const float* __restrict__ Wk,
    const float* __restrict__ Wv,
    unsigned short* __restrict__ qo, unsigned short* __restrict__ ko,
    unsigned short* __restrict__ vo)
{
    __shared__ unsigned short As[128][72];  // stride 72 bf16 = 36 dwords -> 4-bank rotate/row
    __shared__ unsigned short Bs[128][72];

    const int z = blockIdx.z;
    const float* W = (z == 0) ? Wq : (z == 1) ? Wk : Wv;
    unsigned short* out = (z == 0) ? qo : (z == 1) ? ko : vo;

    const int m0 = blockIdx.x * 128;
    const int n0 = blockIdx.y * 128;
    const int t = threadIdx.x;
    const int lane = t & 63;
    const int wave = t >> 6;
    const int wm = wave >> 1, wn = wave & 1;
    const int g = lane >> 4, c = lane & 15;

    f32x4 acc[4][4] = {};

    const int lrow = t >> 4;    // 0..15
    const int lcol4 = t & 15;   // float4 column

    for (int kt = 0; kt < 16; ++kt) {
        const int kbase = kt * 64;
#pragma unroll
        for (int p = 0; p < 8; ++p) {
            const int row = lrow + p * 16;
            const float4 a4 = *reinterpret_cast<const float4*>(
                &X[(size_t)(m0 + row) * 1024 + kbase + lcol4 * 4]);
            const float4 b4 = *reinterpret_cast<const float4*>(
                &W[(size_t)(n0 + row) * 1024 + kbase + lcol4 * 4]);
            ushort4v av, bv;
            av[0] = f2bfu(a4.x); av[1] = f2bfu(a4.y); av[2] = f2bfu(a4.z); av[3] = f2bfu(a4.w);
            bv[0] = f2bfu(b4.x); bv[1] = f2bfu(b4.y); bv[2] = f2bfu(b4.z); bv[3] = f2bfu(b4.w);
            *reinterpret_cast<ushort4v*>(&As[row][lcol4 * 4]) = av;
            *reinterpret_cast<ushort4v*>(&Bs[row][lcol4 * 4]) = bv;
        }
        __syncthreads();
#pragma unroll
        for (int ks = 0; ks < 2; ++ks) {
            short8 bf[4];
#pragma unroll
            for (int nt = 0; nt < 4; ++nt)
                bf[nt] = *reinterpret_cast<const short8*>(&Bs[wn * 64 + nt * 16 + c][ks * 32 + g * 8]);
#pragma unroll
            for (int mt = 0; mt < 4; ++mt) {
                const short8 af = *reinterpret_cast<const short8*>(&As[wm * 64 + mt * 16 + c][ks * 32 + g * 8]);
#pragma unroll
                for (int nt = 0; nt < 4; ++nt)
                    acc[mt][nt] = __builtin_amdgcn_mfma_f32_16x16x32_bf16(af, bf[nt], acc[mt][nt], 0, 0, 0);
            }
        }
        __syncthreads();
    }

    // Epilogue: scatter to [B,H,S,DH] bf16.
#pragma unroll
    for (int mt = 0; mt < 4; ++mt)
#pragma unroll
        for (int nt = 0; nt < 4; ++nt)
#pragma unroll
            for (int r = 0; r < 4; ++r) {
                const int m = m0 + wm * 64 + mt * 16 + g * 4 + r;  // b*S+s
                const int n = n0 + wn * 64 + nt * 16 + c;          // h*64+d
                const int b = m >> 11, s = m & 2047;
                const int h = n >> 6, d = n & 63;
                out[((size_t)(b * Hq + h) * Sq + s) * DHq + d] = f2bfu(acc[mt][nt][r]);
            }
}

// ---------------------------------------------------------------------------
// Kernel 2: causal flash attention. One block per (q-block of 64, b*H+h).
// 4 waves, each owns 16 q-rows. K/V staged in LDS per 64-key tile (V transposed).
// ---------------------------------------------------------------------------
__global__ __launch_bounds__(256) void attn(
    const unsigned short* __restrict__ Q, const unsigned short* __restrict__ K,
    const unsigned short* __restrict__ V, unsigned short* __restrict__ O)
{
    __shared__ unsigned short Ks[64][72];    // [key][dh]
    __shared__ unsigned short VTs[64][72];   // [dh][key]
    __shared__ unsigned short Pw[4][16][72]; // per-wave P transpose buffer

    const int qb = blockIdx.x, bh = blockIdx.y;
    const int t = threadIdx.x, lane = t & 63, wave = t >> 6;
    const int g = lane >> 4, c = lane & 15;
    const size_t base = (size_t)bh * Sq * DHq;

    // Q fragments (row = c, k = ks*32 + g*8 + j)
    short8 qf[2];
    {
        const int qrow = qb * 64 + wave * 16 + c;
        qf[0] = *reinterpret_cast<const short8*>(&Q[base + (size_t)qrow * 64 + g * 8]);
        qf[1] = *reinterpret_cast<const short8*>(&Q[base + (size_t)qrow * 64 + 32 + g * 8]);
    }

    float m_r[4], l_r[4];
    f32x4 oacc[4] = {};
#pragma unroll
    for (int r = 0; r < 4; ++r) { m_r[r] = -3.0e38f; l_r[r] = 0.f; }

    const int srow = t >> 3, scol8 = t & 7;

    for (int kb = 0; kb <= qb; ++kb) {
        __syncthreads();
#pragma unroll
        for (int p = 0; p < 2; ++p) {
            const int row = srow + p * 32;
            const short8 kv = *reinterpret_cast<const short8*>(
                &K[base + (size_t)(kb * 64 + row) * 64 + scol8 * 8]);
            *reinterpret_cast<short8*>(&Ks[row][scol8 * 8]) = kv;
            const short8 vv = *reinterpret_cast<const short8*>(
                &V[base + (size_t)(kb * 64 + row) * 64 + scol8 * 8]);
#pragma unroll
            for (int j = 0; j < 8; ++j)
                VTs[scol8 * 8 + j][row] = (unsigned short)vv[j];
        }
        __syncthreads();

        // S-tile [16 q][64 key]
        f32x4 sacc[4] = {};
#pragma unroll
        for (int ks = 0; ks < 2; ++ks)
#pragma unroll
            for (int kt = 0; kt < 4; ++kt) {
                const short8 kf = *reinterpret_cast<const short8*>(&Ks[kt * 16 + c][ks * 32 + g * 8]);
                sacc[kt] = __builtin_amdgcn_mfma_f32_16x16x32_bf16(qf[ks], kf, sacc[kt], 0, 0, 0);
            }

        // scale + causal mask
        float sv[4][4];
        const bool diag = (kb == qb);
#pragma unroll
        for (int kt = 0; kt < 4; ++kt)
#pragma unroll
            for (int r = 0; r < 4; ++r) {
                float s = sacc[kt][r] * 0.125f;  // 1/sqrt(64)
                if (diag) {
                    const int key = kt * 16 + c;
                    const int qr = wave * 16 + g * 4 + r;
                    if (key > qr) s = -3.0e38f;
                }
                sv[kt][r] = s;
            }

        // online softmax
        float alpha[4];
#pragma unroll
        for (int r = 0; r < 4; ++r) {
            float mm = fmaxf(fmaxf(sv[0][r], sv[1][r]), fmaxf(sv[2][r], sv[3][r]));
#pragma unroll
            for (int off = 1; off < 16; off <<= 1) mm = fmaxf(mm, __shfl_xor(mm, off));
            const float mn = fmaxf(m_r[r], mm);
            alpha[r] = __expf(m_r[r] - mn);
            m_r[r] = mn;
        }
#pragma unroll
        for (int r = 0; r < 4; ++r) {
            float rs = 0.f;
#pragma unroll
            for (int kt = 0; kt < 4; ++kt) {
                const float p = __expf(sv[kt][r] - m_r[r]);
                sv[kt][r] = p;
                rs += p;
            }
#pragma unroll
            for (int off = 1; off < 16; off <<= 1) rs += __shfl_xor(rs, off);
            l_r[r] = l_r[r] * alpha[r] + rs;
#pragma unroll
            for (int dt = 0; dt < 4; ++dt) oacc[dt][r] *= alpha[r];
        }

        // P -> bf16 -> per-wave LDS transpose -> A-fragments
#pragma unroll
        for (int kt = 0; kt < 4; ++kt)
#pragma unroll
            for (int r = 0; r < 4; ++r)
                Pw[wave][g * 4 + r][kt * 16 + c] = f2bfu(sv[kt][r]);
        short8 pf[2];
        pf[0] = *reinterpret_cast<const short8*>(&Pw[wave][c][g * 8]);
        pf[1] = *reinterpret_cast<const short8*>(&Pw[wave][c][32 + g * 8]);

        // O += P @ V
#pragma unroll
        for (int ks = 0; ks < 2; ++ks)
#pragma unroll
            for (int dt = 0; dt < 4; ++dt) {
                const short8 vf = *reinterpret_cast<const short8*>(&VTs[dt * 16 + c][ks * 32 + g * 8]);
                oacc[dt] = __builtin_amdgcn_mfma_f32_16x16x32_bf16(ks == 0 ? pf[0] : pf[1], vf, oacc[dt], 0, 0, 0);
            }
    }

    // epilogue: O /= l, write [B,S,D] bf16
    const int b = bh >> 4, h = bh & 15;
#pragma unroll
    for (int dt = 0; dt < 4; ++dt)
#pragma unroll
        for (int r = 0; r < 4; ++r) {
            const int s = qb * 64 + wave * 16 + g * 4 + r;
            const float ov = oacc[dt][r] / l_r[r];
            O[((size_t)b * Sq + s) * Dq + h * 64 + dt * 16 + c] = f2bfu(ov);
        }
}

// ---------------------------------------------------------------------------
// Kernel 3: output projection. out = Z @ Wo^T + bo (fp32 out).
// ---------------------------------------------------------------------------
__global__ __launch_bounds__(256) void proj_gemm(
    const unsigned short* __restrict__ Z, const float* __restrict__ Wo,
    const float* __restrict__ bo, float* __restrict__ out)
{
    __shared__ unsigned short As[128][72];
    __shared__ unsigned short Bs[128][72];

    const int m0 = blockIdx.x * 128;
    const int n0 = blockIdx.y * 128;
    const int t = threadIdx.x;
    const int lane = t & 63;
    const int wave = t >> 6;
    const int wm = wave >> 1, wn = wave & 1;
    const int g = lane >> 4, c = lane & 15;

    f32x4 acc[4][4] = {};

    const int lrow = t >> 4, lcol4 = t & 15;      // B staging (fp32 source)
    const int arow = t >> 3, acol8 = t & 7;       // A staging (bf16 source)

    for (int kt = 0; kt < 16; ++kt) {
        const int kbase = kt * 64;
#pragma unroll
        for (int p = 0; p < 4; ++p) {
            const int row = arow + p * 32;
            const short8 a8 = *reinterpret_cast<const short8*>(
                &Z[(size_t)(m0 + row) * 1024 + kbase + acol8 * 8]);
            *reinterpret_cast<short8*>(&As[row][acol8 * 8]) = a8;
        }
#pragma unroll
        for (int p = 0; p < 8; ++p) {
            const int row = lrow + p * 16;
            const float4 b4 = *reinterpret_cast<const float4*>(
                &Wo[(size_t)(n0 + row) * 1024 + kbase + lcol4 * 4]);
            ushort4v bv;
            bv[0] = f2bfu(b4.x); bv[1] = f2bfu(b4.y); bv[2] = f2bfu(b4.z); bv[3] = f2bfu(b4.w);
            *reinterpret_cast<ushort4v*>(&Bs[row][lcol4 * 4]) = bv;
        }
        __syncthreads();
#pragma unroll
        for (int ks = 0; ks < 2; ++ks) {
            short8 bf[4];
#pragma unroll
            for (int nt = 0; nt < 4; ++nt)
                bf[nt] = *reinterpret_cast<const short8*>(&Bs[wn * 64 + nt * 16 + c][ks * 32 + g * 8]);
#pragma unroll
            for (int mt = 0; mt < 4; ++mt) {
                const short8 af = *reinterpret_cast<const short8*>(&As[wm * 64 + mt * 16 + c][ks * 32 + g * 8]);
#pragma unroll
                for (int nt = 0; nt < 4; ++nt)
                    acc[mt][nt] = __builtin_amdgcn_mfma_f32_16x16x32_bf16(af, bf[nt], acc[mt][nt], 0, 0, 0);
            }
        }
        __syncthreads();
    }

#pragma unroll
    for (int nt = 0; nt < 4; ++nt) {
        const int n = n0 + wn * 64 + nt * 16 + c;
        const float bias = bo[n];
#pragma unroll
        for (int mt = 0; mt < 4; ++mt)
#pragma unroll
            for (int r = 0; r < 4; ++r) {
                const int m = m0 + wm * 64 + mt * 16 + g * 4 + r;
                out[(size_t)m * 1024 + n] = acc[mt][nt][r] + bias;
            }
    }
}

// ---------------------------------------------------------------------------
extern "C" void kernel_launch(void* const* d_in, const int* in_sizes, int n_in,
                              void* d_out, int out_size, void* d_ws, size_t ws_size,
                              hipStream_t stream) {
    const float* X  = (const float*)d_in[0];
    const float* Wq = (const float*)d_in[1];
    const float* Wk = (const float*)d_in[2];
    const float* Wv = (const float*)d_in[3];
    const float* Wo = (const float*)d_in[4];
    const float* bo = (const float*)d_in[5];
    float* out = (float*)d_out;

    const size_t elems = (size_t)Bq * Hq * Sq * DHq;  // 8,388,608
    unsigned short* q = (unsigned short*)d_ws;
    unsigned short* k = q + elems;
    unsigned short* v = k + elems;
    unsigned short* o = v + elems;

    dim3 gq((Bq * Sq) / 128, Dq / 128, 3);
    qkv_gemm<<<gq, 256, 0, stream>>>(X, Wq, Wk, Wv, q, k, v);

    dim3 ga(Sq / 64, Bq * Hq, 1);
    attn<<<ga, 256, 0, stream>>>(q, k, v, o);

    dim3 gp((Bq * Sq) / 128, Dq / 128, 1);
    proj_gemm<<<gp, 256, 0, stream>>>(o, Wo, bo, out);
}

// Round 2
// 428.211 us; speedup vs baseline: 1.0296x; 1.0296x over previous
//
#include <hip/hip_runtime.h>
#include <hip/hip_bf16.h>

// MHA forward: B=4, S=2048, D=1024, H=16, DH=64. fp32 in/out, bf16 MFMA inside.

#define Bq 4
#define Sq 2048
#define Dq 1024
#define Hq 16
#define DHq 64

typedef __attribute__((ext_vector_type(8))) short short8;
typedef __attribute__((ext_vector_type(4))) float f32x4;
typedef __attribute__((ext_vector_type(4))) unsigned short ushort4v;
typedef __attribute__((ext_vector_type(2))) unsigned int uint2v;

static __device__ __forceinline__ unsigned short f2bfu(float f) {
    union { __hip_bfloat16 h; unsigned short u; } cv;
    cv.h = __float2bfloat16(f);
    return cv.u;
}
static __device__ __forceinline__ unsigned int pkbf(float lo, float hi) {
    return (unsigned int)f2bfu(lo) | ((unsigned int)f2bfu(hi) << 16);
}

// ---------------------------------------------------------------------------
// Kernel 1: QKV projections. Y = X @ W^T.
//  VT=false: out layout [B,H,S,DH]   (Q, K)
//  VT=true : out layout [B,H,DH,S]   (V transposed, via operand-swapped MFMA)
// Tile 128x128, BK=64, 4 waves (2x2), each wave 64x64 via 4x4 16x16x32 MFMAs.
// ---------------------------------------------------------------------------
template<bool VT>
__global__ __launch_bounds__(256) void qkv_gemm(
    const float* __restrict__ X,
    const float* __restrict__ W0, const float* __restrict__ W1,
    unsigned short* __restrict__ o0, unsigned short* __restrict__ o1)
{
    __shared__ unsigned short As[128][72];
    __shared__ unsigned short Bs[128][72];

    const float* W = blockIdx.z ? W1 : W0;
    unsigned short* out = blockIdx.z ? o1 : o0;

    const int m0 = blockIdx.x * 128;
    const int n0 = blockIdx.y * 128;
    const int t = threadIdx.x;
    const int lane = t & 63;
    const int wave = t >> 6;
    const int wm = wave >> 1, wn = wave & 1;
    const int g = lane >> 4, c = lane & 15;

    f32x4 acc[4][4] = {};

    const int lrow = t >> 4;    // 0..15
    const int lcol4 = t & 15;   // float4 column

    for (int kt = 0; kt < 16; ++kt) {
        const int kbase = kt * 64;
#pragma unroll
        for (int p = 0; p < 8; ++p) {
            const int row = lrow + p * 16;
            const float4 a4 = *reinterpret_cast<const float4*>(
                &X[(size_t)(m0 + row) * 1024 + kbase + lcol4 * 4]);
            const float4 b4 = *reinterpret_cast<const float4*>(
                &W[(size_t)(n0 + row) * 1024 + kbase + lcol4 * 4]);
            ushort4v av, bv;
            av[0] = f2bfu(a4.x); av[1] = f2bfu(a4.y); av[2] = f2bfu(a4.z); av[3] = f2bfu(a4.w);
            bv[0] = f2bfu(b4.x); bv[1] = f2bfu(b4.y); bv[2] = f2bfu(b4.z); bv[3] = f2bfu(b4.w);
            *reinterpret_cast<ushort4v*>(&As[row][lcol4 * 4]) = av;
            *reinterpret_cast<ushort4v*>(&Bs[row][lcol4 * 4]) = bv;
        }
        __syncthreads();
#pragma unroll
        for (int ks = 0; ks < 2; ++ks) {
            short8 bf[4];
#pragma unroll
            for (int nt = 0; nt < 4; ++nt)
                bf[nt] = *reinterpret_cast<const short8*>(&Bs[wn * 64 + nt * 16 + c][ks * 32 + g * 8]);
#pragma unroll
            for (int mt = 0; mt < 4; ++mt) {
                const short8 af = *reinterpret_cast<const short8*>(&As[wm * 64 + mt * 16 + c][ks * 32 + g * 8]);
#pragma unroll
                for (int nt = 0; nt < 4; ++nt) {
                    if (VT)
                        acc[mt][nt] = __builtin_amdgcn_mfma_f32_16x16x32_bf16(bf[nt], af, acc[mt][nt], 0, 0, 0);
                    else
                        acc[mt][nt] = __builtin_amdgcn_mfma_f32_16x16x32_bf16(af, bf[nt], acc[mt][nt], 0, 0, 0);
                }
            }
        }
        __syncthreads();
    }

#pragma unroll
    for (int mt = 0; mt < 4; ++mt)
#pragma unroll
        for (int nt = 0; nt < 4; ++nt)
#pragma unroll
            for (int r = 0; r < 4; ++r) {
                if (VT) {
                    // acc row = n-local, col = m-local
                    const int m = m0 + wm * 64 + mt * 16 + c;
                    const int n = n0 + wn * 64 + nt * 16 + g * 4 + r;
                    const int b = m >> 11, s = m & 2047;
                    const int h = n >> 6, d = n & 63;
                    out[((size_t)(b * Hq + h) * DHq + d) * Sq + s] = f2bfu(acc[mt][nt][r]);
                } else {
                    const int m = m0 + wm * 64 + mt * 16 + g * 4 + r;
                    const int n = n0 + wn * 64 + nt * 16 + c;
                    const int b = m >> 11, s = m & 2047;
                    const int h = n >> 6, d = n & 63;
                    out[((size_t)(b * Hq + h) * Sq + s) * DHq + d] = f2bfu(acc[mt][nt][r]);
                }
            }
}

// ---------------------------------------------------------------------------
// Kernel 2: causal flash attention, barrier-free.
// 1D grid of 2048 blocks, 4 waves each; wave owns a 16-row q-tile.
// Swapped QK^T (S^T = K·Q^T) makes softmax lane-local (q = lane&15);
// PV computed as O^T = V^T · P^T with V^T read straight from ws.
// Only LDS: tiny per-wave P^T repack buffer (same-wave, no barriers).
// ---------------------------------------------------------------------------
__global__ __launch_bounds__(256) void attn(
    const unsigned short* __restrict__ Q, const unsigned short* __restrict__ K,
    const unsigned short* __restrict__ Vt, unsigned short* __restrict__ O)
{
    __shared__ unsigned short Pt[4][16][80];  // [wave][q][key] bf16

    // XCD swizzle: all 32 q-blocks of one bh land on one XCD (bid % 8 fixed);
    // qb reversed so the long causal rows launch first.
    const int bid = blockIdx.x;
    const int bh = (bid & 7) | ((bid >> 8) << 3);
    const int qb = 31 - ((bid >> 3) & 31);

    const int t = threadIdx.x, lane = t & 63, wave = t >> 6;
    const int g = lane >> 4, c = lane & 15;
    const int qt = qb * 4 + wave;             // q-tile (16 rows)
    const size_t base = (size_t)bh * Sq * DHq;

    // Q as B-fragment: B[k][q=c] = Q[qt*16+c][k]
    const short8 qf0 = *reinterpret_cast<const short8*>(&Q[base + (size_t)(qt * 16 + c) * 64 + g * 8]);
    const short8 qf1 = *reinterpret_cast<const short8*>(&Q[base + (size_t)(qt * 16 + c) * 64 + 32 + g * 8]);

    float m_r = -3.0e38f, l_r = 0.f;
    f32x4 oacc[4] = {};

    for (int kb = 0; kb <= qb; ++kb) {
        // ---- S^T = K · Q^T  (acc: row=key_local=g*4+r per kt, col=q=c)
        const unsigned short* Kt = &K[base + (size_t)kb * 64 * 64];
        f32x4 st[4] = {};
#pragma unroll
        for (int kt = 0; kt < 4; ++kt) {
            const unsigned short* kr = &Kt[(size_t)(kt * 16 + c) * 64];
            const short8 kf0 = *reinterpret_cast<const short8*>(&kr[g * 8]);
            const short8 kf1 = *reinterpret_cast<const short8*>(&kr[32 + g * 8]);
            st[kt] = __builtin_amdgcn_mfma_f32_16x16x32_bf16(kf0, qf0, st[kt], 0, 0, 0);
            st[kt] = __builtin_amdgcn_mfma_f32_16x16x32_bf16(kf1, qf1, st[kt], 0, 0, 0);
        }

        // ---- issue V^T loads early; latency hides under softmax VALU
        const unsigned short* Vb = &Vt[base + (size_t)kb * 64];
        short8 vf0[4], vf1[4];
#pragma unroll
        for (int dt = 0; dt < 4; ++dt) {
            const unsigned short* vr = &Vb[(size_t)(dt * 16 + c) * Sq];
            vf0[dt] = *reinterpret_cast<const short8*>(&vr[g * 8]);
            vf1[dt] = *reinterpret_cast<const short8*>(&vr[32 + g * 8]);
        }

        // ---- scale + causal mask (key_local = kt*16+g*4+r, q_local = wave*16+c)
        float p[4][4];
        const bool diag = (kb == qb);
#pragma unroll
        for (int kt = 0; kt < 4; ++kt)
#pragma unroll
            for (int r = 0; r < 4; ++r) {
                float s = st[kt][r] * 0.125f;   // 1/sqrt(64)
                if (diag && (kt * 16 + g * 4 + r > wave * 16 + c)) s = -3.0e38f;
                p[kt][r] = s;
            }

        // ---- lane-local online softmax (16 in-lane + 2 shfl)
        float mm = p[0][0];
#pragma unroll
        for (int kt = 0; kt < 4; ++kt)
#pragma unroll
            for (int r = 0; r < 4; ++r) mm = fmaxf(mm, p[kt][r]);
        mm = fmaxf(mm, __shfl_xor(mm, 16));
        mm = fmaxf(mm, __shfl_xor(mm, 32));
        const float mn = fmaxf(m_r, mm);
        const float alpha = __expf(m_r - mn);
        m_r = mn;
        float rs = 0.f;
#pragma unroll
        for (int kt = 0; kt < 4; ++kt)
#pragma unroll
            for (int r = 0; r < 4; ++r) {
                const float e = __expf(p[kt][r] - mn);
                p[kt][r] = e;
                rs += e;
            }
        rs += __shfl_xor(rs, 16);
        rs += __shfl_xor(rs, 32);
        l_r = l_r * alpha + rs;
#pragma unroll
        for (int dt = 0; dt < 4; ++dt)
#pragma unroll
            for (int r = 0; r < 4; ++r) oacc[dt][r] *= alpha;

        // ---- P^T -> bf16 -> per-wave LDS repack (same-wave, no barrier)
#pragma unroll
        for (int kt = 0; kt < 4; ++kt) {
            uint2v u;
            u[0] = pkbf(p[kt][0], p[kt][1]);
            u[1] = pkbf(p[kt][2], p[kt][3]);
            *reinterpret_cast<uint2v*>(&Pt[wave][c][kt * 16 + g * 4]) = u;
        }
        const short8 pb0 = *reinterpret_cast<const short8*>(&Pt[wave][c][g * 8]);
        const short8 pb1 = *reinterpret_cast<const short8*>(&Pt[wave][c][32 + g * 8]);

        // ---- O^T += V^T · P^T  (acc: row=d_local=g*4+r per dt, col=q=c)
#pragma unroll
        for (int dt = 0; dt < 4; ++dt) {
            oacc[dt] = __builtin_amdgcn_mfma_f32_16x16x32_bf16(vf0[dt], pb0, oacc[dt], 0, 0, 0);
            oacc[dt] = __builtin_amdgcn_mfma_f32_16x16x32_bf16(vf1[dt], pb1, oacc[dt], 0, 0, 0);
        }
    }

    // ---- epilogue: O[b, q, h*64+d] = O^T[d][q] / l,  packed 4-bf16 stores
    const float rl = 1.0f / l_r;
    const int b = bh >> 4, h = bh & 15;
    const size_t orow = ((size_t)b * Sq + qt * 16 + c) * Dq + h * 64;
#pragma unroll
    for (int dt = 0; dt < 4; ++dt) {
        uint2v u;
        u[0] = pkbf(oacc[dt][0] * rl, oacc[dt][1] * rl);
        u[1] = pkbf(oacc[dt][2] * rl, oacc[dt][3] * rl);
        *reinterpret_cast<uint2v*>(&O[orow + dt * 16 + g * 4]) = u;
    }
}

// ---------------------------------------------------------------------------
// Kernel 3: output projection. out = Z @ Wo^T + bo (fp32 out).
// ---------------------------------------------------------------------------
__global__ __launch_bounds__(256) void proj_gemm(
    const unsigned short* __restrict__ Z, const float* __restrict__ Wo,
    const float* __restrict__ bo, float* __restrict__ out)
{
    __shared__ unsigned short As[128][72];
    __shared__ unsigned short Bs[128][72];

    const int m0 = blockIdx.x * 128;
    const int n0 = blockIdx.y * 128;
    const int t = threadIdx.x;
    const int lane = t & 63;
    const int wave = t >> 6;
    const int wm = wave >> 1, wn = wave & 1;
    const int g = lane >> 4, c = lane & 15;

    f32x4 acc[4][4] = {};

    const int lrow = t >> 4, lcol4 = t & 15;      // B staging (fp32 source)
    const int arow = t >> 3, acol8 = t & 7;       // A staging (bf16 source)

    for (int kt = 0; kt < 16; ++kt) {
        const int kbase = kt * 64;
#pragma unroll
        for (int p = 0; p < 4; ++p) {
            const int row = arow + p * 32;
            const short8 a8 = *reinterpret_cast<const short8*>(
                &Z[(size_t)(m0 + row) * 1024 + kbase + acol8 * 8]);
            *reinterpret_cast<short8*>(&As[row][acol8 * 8]) = a8;
        }
#pragma unroll
        for (int p = 0; p < 8; ++p) {
            const int row = lrow + p * 16;
            const float4 b4 = *reinterpret_cast<const float4*>(
                &Wo[(size_t)(n0 + row) * 1024 + kbase + lcol4 * 4]);
            ushort4v bv;
            bv[0] = f2bfu(b4.x); bv[1] = f2bfu(b4.y); bv[2] = f2bfu(b4.z); bv[3] = f2bfu(b4.w);
            *reinterpret_cast<ushort4v*>(&Bs[row][lcol4 * 4]) = bv;
        }
        __syncthreads();
#pragma unroll
        for (int ks = 0; ks < 2; ++ks) {
            short8 bf[4];
#pragma unroll
            for (int nt = 0; nt < 4; ++nt)
                bf[nt] = *reinterpret_cast<const short8*>(&Bs[wn * 64 + nt * 16 + c][ks * 32 + g * 8]);
#pragma unroll
            for (int mt = 0; mt < 4; ++mt) {
                const short8 af = *reinterpret_cast<const short8*>(&As[wm * 64 + mt * 16 + c][ks * 32 + g * 8]);
#pragma unroll
                for (int nt = 0; nt < 4; ++nt)
                    acc[mt][nt] = __builtin_amdgcn_mfma_f32_16x16x32_bf16(af, bf[nt], acc[mt][nt], 0, 0, 0);
            }
        }
        __syncthreads();
    }

#pragma unroll
    for (int nt = 0; nt < 4; ++nt) {
        const int n = n0 + wn * 64 + nt * 16 + c;
        const float bias = bo[n];
#pragma unroll
        for (int mt = 0; mt < 4; ++mt)
#pragma unroll
            for (int r = 0; r < 4; ++r) {
                const int m = m0 + wm * 64 + mt * 16 + g * 4 + r;
                out[(size_t)m * 1024 + n] = acc[mt][nt][r] + bias;
            }
    }
}

// ---------------------------------------------------------------------------
extern "C" void kernel_launch(void* const* d_in, const int* in_sizes, int n_in,
                              void* d_out, int out_size, void* d_ws, size_t ws_size,
                              hipStream_t stream) {
    const float* X  = (const float*)d_in[0];
    const float* Wq = (const float*)d_in[1];
    const float* Wk = (const float*)d_in[2];
    const float* Wv = (const float*)d_in[3];
    const float* Wo = (const float*)d_in[4];
    const float* bo = (const float*)d_in[5];
    float* out = (float*)d_out;

    const size_t elems = (size_t)Bq * Hq * Sq * DHq;  // 8,388,608
    unsigned short* q  = (unsigned short*)d_ws;
    unsigned short* k  = q + elems;
    unsigned short* vt = k + elems;
    unsigned short* o  = vt + elems;

    dim3 gq((Bq * Sq) / 128, Dq / 128, 2);
    qkv_gemm<false><<<gq, 256, 0, stream>>>(X, Wq, Wk, q, k);
    dim3 gv((Bq * Sq) / 128, Dq / 128, 1);
    qkv_gemm<true><<<gv, 256, 0, stream>>>(X, Wv, Wv, vt, vt);

    attn<<<dim3(2048), 256, 0, stream>>>(q, k, vt, o);

    dim3 gp((Bq * Sq) / 128, Dq / 128, 1);
    proj_gemm<<<gp, 256, 0, stream>>>(o, Wo, bo, out);
}

// Round 3
// 219.193 us; speedup vs baseline: 2.0114x; 1.9536x over previous
//
#include <hip/hip_runtime.h>
#include <hip/hip_bf16.h>

// MHA forward: B=4, S=2048, D=1024, H=16, DH=64. fp32 in/out, bf16 MFMA inside.

#define Bq 4
#define Sq 2048
#define Dq 1024
#define Hq 16
#define DHq 64

typedef __attribute__((ext_vector_type(8))) short short8;
typedef __attribute__((ext_vector_type(4))) float f32x4;
typedef __attribute__((ext_vector_type(4))) unsigned short ushort4v;
typedef __attribute__((ext_vector_type(2))) unsigned int uint2v;

static __device__ __forceinline__ unsigned short f2bfu(float f) {
    union { __hip_bfloat16 h; unsigned short u; } cv;
    cv.h = __float2bfloat16(f);
    return cv.u;
}
static __device__ __forceinline__ unsigned int pkbf(float lo, float hi) {
    return (unsigned int)f2bfu(lo) | ((unsigned int)f2bfu(hi) << 16);
}

// ---------------------------------------------------------------------------
// Fragment-order layouts (per bh block of 131072 ushorts):
//  Q/K (A-frag over [s,d]): off = (s>>4)*1024 + (d>>5)*512 + ((d>>3)&3)*128
//                                 + (s&15)*8 + (d&7)
//  V   (A-frag over [d,s]): off = (s>>6)*4096 + ((d>>4)&3)*1024 + ((s>>5)&1)*512
//                                 + ((s>>3)&3)*128 + (d&15)*8 + (s&7)
// so attn's per-lane 16B fragment read is tile_base + lane*16 (fully coalesced).
// ---------------------------------------------------------------------------

// ---------------------------------------------------------------------------
// Kernel 1: QKV projections. Y = X @ W^T, scattered to fragment-order layouts.
//  VT=false: Q (z=0, scaled by 1/8) and K (z=1)
//  VT=true : V via operand-swapped MFMA (acc holds V^T)
// ---------------------------------------------------------------------------
template<bool VT>
__global__ __launch_bounds__(256) void qkv_gemm(
    const float* __restrict__ X,
    const float* __restrict__ W0, const float* __restrict__ W1,
    unsigned short* __restrict__ o0, unsigned short* __restrict__ o1)
{
    __shared__ unsigned short As[128][72];
    __shared__ unsigned short Bs[128][72];

    const float* W = blockIdx.z ? W1 : W0;
    unsigned short* out = blockIdx.z ? o1 : o0;
    const float oscale = (!VT && blockIdx.z == 0) ? 0.125f : 1.0f;  // fold 1/sqrt(DH) into Q

    const int m0 = blockIdx.x * 128;
    const int n0 = blockIdx.y * 128;
    const int t = threadIdx.x;
    const int lane = t & 63;
    const int wave = t >> 6;
    const int wm = wave >> 1, wn = wave & 1;
    const int g = lane >> 4, c = lane & 15;

    f32x4 acc[4][4] = {};

    const int lrow = t >> 4;    // 0..15
    const int lcol4 = t & 15;   // float4 column

    for (int kt = 0; kt < 16; ++kt) {
        const int kbase = kt * 64;
#pragma unroll
        for (int p = 0; p < 8; ++p) {
            const int row = lrow + p * 16;
            const float4 a4 = *reinterpret_cast<const float4*>(
                &X[(size_t)(m0 + row) * 1024 + kbase + lcol4 * 4]);
            const float4 b4 = *reinterpret_cast<const float4*>(
                &W[(size_t)(n0 + row) * 1024 + kbase + lcol4 * 4]);
            ushort4v av, bv;
            av[0] = f2bfu(a4.x); av[1] = f2bfu(a4.y); av[2] = f2bfu(a4.z); av[3] = f2bfu(a4.w);
            bv[0] = f2bfu(b4.x); bv[1] = f2bfu(b4.y); bv[2] = f2bfu(b4.z); bv[3] = f2bfu(b4.w);
            *reinterpret_cast<ushort4v*>(&As[row][lcol4 * 4]) = av;
            *reinterpret_cast<ushort4v*>(&Bs[row][lcol4 * 4]) = bv;
        }
        __syncthreads();
#pragma unroll
        for (int ks = 0; ks < 2; ++ks) {
            short8 bf[4];
#pragma unroll
            for (int nt = 0; nt < 4; ++nt)
                bf[nt] = *reinterpret_cast<const short8*>(&Bs[wn * 64 + nt * 16 + c][ks * 32 + g * 8]);
#pragma unroll
            for (int mt = 0; mt < 4; ++mt) {
                const short8 af = *reinterpret_cast<const short8*>(&As[wm * 64 + mt * 16 + c][ks * 32 + g * 8]);
#pragma unroll
                for (int nt = 0; nt < 4; ++nt) {
                    if (VT)
                        acc[mt][nt] = __builtin_amdgcn_mfma_f32_16x16x32_bf16(bf[nt], af, acc[mt][nt], 0, 0, 0);
                    else
                        acc[mt][nt] = __builtin_amdgcn_mfma_f32_16x16x32_bf16(af, bf[nt], acc[mt][nt], 0, 0, 0);
                }
            }
        }
        __syncthreads();
    }

#pragma unroll
    for (int mt = 0; mt < 4; ++mt)
#pragma unroll
        for (int nt = 0; nt < 4; ++nt)
#pragma unroll
            for (int r = 0; r < 4; ++r) {
                if (VT) {
                    // acc row (g*4+r) = feature-local, col (c) = token-local
                    const int m = m0 + wm * 64 + mt * 16 + c;           // token
                    const int n = n0 + wn * 64 + nt * 16 + g * 4 + r;   // feature
                    const int bb = m >> 11, s = m & 2047;
                    const int h = n >> 6, d = n & 63;
                    const size_t off = (size_t)(bb * Hq + h) * 131072
                        + (s >> 6) * 4096 + ((d >> 4) & 3) * 1024 + ((s >> 5) & 1) * 512
                        + ((s >> 3) & 3) * 128 + (d & 15) * 8 + (s & 7);
                    out[off] = f2bfu(acc[mt][nt][r]);
                } else {
                    const int m = m0 + wm * 64 + mt * 16 + g * 4 + r;   // token
                    const int n = n0 + wn * 64 + nt * 16 + c;           // feature
                    const int bb = m >> 11, s = m & 2047;
                    const int h = n >> 6, d = n & 63;
                    const size_t off = (size_t)(bb * Hq + h) * 131072
                        + (s >> 4) * 1024 + (d >> 5) * 512 + ((d >> 3) & 3) * 128
                        + (s & 15) * 8 + (d & 7);
                    out[off] = f2bfu(acc[mt][nt][r] * oscale);
                }
            }
}

// ---------------------------------------------------------------------------
// Kernel 2: causal flash attention, barrier-free, fragment-order inputs.
// 1024 blocks; block handles qb=pair then qb=31-pair (exactly 33 iterations).
// K double-buffered in registers (prefetch next tile during softmax); V issued
// right after QK. sched_barrier(0) pins the loads above the softmax VALU.
// ---------------------------------------------------------------------------
#define ATTN_STEP(KC, KN, IB)                                                  \
  {                                                                            \
    f32x4 st[4] = {};                                                          \
    _Pragma("unroll")                                                          \
    for (int k2 = 0; k2 < 4; ++k2) {                                           \
      st[k2] = __builtin_amdgcn_mfma_f32_16x16x32_bf16(KC[2 * k2], qf0, st[k2], 0, 0, 0);     \
      st[k2] = __builtin_amdgcn_mfma_f32_16x16x32_bf16(KC[2 * k2 + 1], qf1, st[k2], 0, 0, 0); \
    }                                                                          \
    short8 vf[8];                                                              \
    {                                                                          \
      const unsigned short* vp = Vb + (size_t)(IB) * 4096 + lane * 8;          \
      _Pragma("unroll")                                                        \
      for (int i = 0; i < 8; ++i) vf[i] = *reinterpret_cast<const short8*>(vp + i * 512); \
    }                                                                          \
    if ((IB) < qb) {                                                           \
      const unsigned short* kp = Kb + (size_t)((IB) + 1) * 4096 + lane * 8;    \
      _Pragma("unroll")                                                        \
      for (int i = 0; i < 8; ++i) KN[i] = *reinterpret_cast<const short8*>(kp + i * 512); \
    }                                                                          \
    __builtin_amdgcn_sched_barrier(0);                                         \
    float p[4][4];                                                             \
    const bool diag = ((IB) == qb);                                            \
    _Pragma("unroll")                                                          \
    for (int kt = 0; kt < 4; ++kt)                                             \
      _Pragma("unroll")                                                        \
      for (int r = 0; r < 4; ++r) {                                            \
        float sv = st[kt][r];                                                  \
        if (diag && (kt * 16 + g * 4 + r > qloc)) sv = -3.0e38f;               \
        p[kt][r] = sv;                                                         \
      }                                                                        \
    float t0 = fmaxf(fmaxf(p[0][0], p[0][1]), fmaxf(p[0][2], p[0][3]));        \
    float t1 = fmaxf(fmaxf(p[1][0], p[1][1]), fmaxf(p[1][2], p[1][3]));        \
    float t2 = fmaxf(fmaxf(p[2][0], p[2][1]), fmaxf(p[2][2], p[2][3]));        \
    float t3 = fmaxf(fmaxf(p[3][0], p[3][1]), fmaxf(p[3][2], p[3][3]));        \
    float mx = fmaxf(fmaxf(t0, t1), fmaxf(t2, t3));                            \
    mx = fmaxf(mx, __shfl_xor(mx, 16));                                        \
    mx = fmaxf(mx, __shfl_xor(mx, 32));                                        \
    if (__any(mx > m_r + 8.f)) {                                               \
      const float mn = fmaxf(m_r, mx);                                         \
      const float alpha = __expf(m_r - mn);                                    \
      l_r *= alpha;                                                            \
      _Pragma("unroll")                                                        \
      for (int dt = 0; dt < 4; ++dt)                                           \
        _Pragma("unroll")                                                      \
        for (int r = 0; r < 4; ++r) oacc[dt][r] *= alpha;                      \
      m_r = mn;                                                                \
    }                                                                          \
    float rs = 0.f;                                                            \
    _Pragma("unroll")                                                          \
    for (int kt = 0; kt < 4; ++kt)                                             \
      _Pragma("unroll")                                                        \
      for (int r = 0; r < 4; ++r) {                                            \
        const float e = __expf(p[kt][r] - m_r);                                \
        p[kt][r] = e;                                                          \
        rs += e;                                                               \
      }                                                                        \
    rs += __shfl_xor(rs, 16);                                                  \
    rs += __shfl_xor(rs, 32);                                                  \
    l_r += rs;                                                                 \
    _Pragma("unroll")                                                          \
    for (int kt = 0; kt < 4; ++kt) {                                           \
      uint2v u;                                                                \
      u[0] = pkbf(p[kt][0], p[kt][1]);                                         \
      u[1] = pkbf(p[kt][2], p[kt][3]);                                         \
      *reinterpret_cast<uint2v*>(&Pt[wave][c][kt * 16 + g * 4]) = u;           \
    }                                                                          \
    const short8 pb0 = *reinterpret_cast<const short8*>(&Pt[wave][c][g * 8]);  \
    const short8 pb1 = *reinterpret_cast<const short8*>(&Pt[wave][c][32 + g * 8]); \
    _Pragma("unroll")                                                          \
    for (int dt = 0; dt < 4; ++dt) {                                           \
      oacc[dt] = __builtin_amdgcn_mfma_f32_16x16x32_bf16(vf[2 * dt], pb0, oacc[dt], 0, 0, 0);     \
      oacc[dt] = __builtin_amdgcn_mfma_f32_16x16x32_bf16(vf[2 * dt + 1], pb1, oacc[dt], 0, 0, 0); \
    }                                                                          \
  }

__global__ __launch_bounds__(256) void attn(
    const unsigned short* __restrict__ Qf, const unsigned short* __restrict__ Kf,
    const unsigned short* __restrict__ Vf, unsigned short* __restrict__ O)
{
    __shared__ unsigned short Pt[4][16][72];

    // bid = xcd(3b) | pair(4b)<<3 | bh_hi(3b)<<7 : all q-work of one bh on one
    // XCD; every block does exactly 33 iterations (qb=pair, then 31-pair).
    const int bid = blockIdx.x;
    const int pair = (bid >> 3) & 15;
    const int bh = (bid & 7) | ((bid >> 7) << 3);

    const int t = threadIdx.x, lane = t & 63, wave = t >> 6;
    const int g = lane >> 4, c = lane & 15;
    const int qloc = wave * 16 + c;
    const size_t base = (size_t)bh * (Sq * DHq);
    const unsigned short* Qb = Qf + base;
    const unsigned short* Kb = Kf + base;
    const unsigned short* Vb = Vf + base;
    const int b = bh >> 4, h = bh & 15;

#pragma unroll 1
    for (int pp = 0; pp < 2; ++pp) {
        const int qb = pp ? (31 - pair) : pair;
        const int qt = qb * 4 + wave;

        const unsigned short* qp = Qb + (size_t)qt * 1024 + lane * 8;
        const short8 qf0 = *reinterpret_cast<const short8*>(qp);
        const short8 qf1 = *reinterpret_cast<const short8*>(qp + 512);

        float m_r = -3.0e38f, l_r = 0.f;
        f32x4 oacc[4] = {};

        short8 ka[8], kb2[8];
        {
            const unsigned short* kp = Kb + lane * 8;
#pragma unroll
            for (int i = 0; i < 8; ++i) ka[i] = *reinterpret_cast<const short8*>(kp + i * 512);
        }
        int ib = 0;
        for (;;) {
            ATTN_STEP(ka, kb2, ib); if (ib == qb) break; ++ib;
            ATTN_STEP(kb2, ka, ib); if (ib == qb) break; ++ib;
        }

        const float rl = 1.0f / l_r;
        const size_t orow = ((size_t)b * Sq + qt * 16 + c) * Dq + h * 64;
#pragma unroll
        for (int dt = 0; dt < 4; ++dt) {
            uint2v u;
            u[0] = pkbf(oacc[dt][0] * rl, oacc[dt][1] * rl);
            u[1] = pkbf(oacc[dt][2] * rl, oacc[dt][3] * rl);
            *reinterpret_cast<uint2v*>(&O[orow + dt * 16 + g * 4]) = u;
        }
    }
}

// ---------------------------------------------------------------------------
// Kernel 3: output projection. out = Z @ Wo^T + bo (fp32 out).
// ---------------------------------------------------------------------------
__global__ __launch_bounds__(256) void proj_gemm(
    const unsigned short* __restrict__ Z, const float* __restrict__ Wo,
    const float* __restrict__ bo, float* __restrict__ out)
{
    __shared__ unsigned short As[128][72];
    __shared__ unsigned short Bs[128][72];

    const int m0 = blockIdx.x * 128;
    const int n0 = blockIdx.y * 128;
    const int t = threadIdx.x;
    const int lane = t & 63;
    const int wave = t >> 6;
    const int wm = wave >> 1, wn = wave & 1;
    const int g = lane >> 4, c = lane & 15;

    f32x4 acc[4][4] = {};

    const int lrow = t >> 4, lcol4 = t & 15;      // B staging (fp32 source)
    const int arow = t >> 3, acol8 = t & 7;       // A staging (bf16 source)

    for (int kt = 0; kt < 16; ++kt) {
        const int kbase = kt * 64;
#pragma unroll
        for (int p = 0; p < 4; ++p) {
            const int row = arow + p * 32;
            const short8 a8 = *reinterpret_cast<const short8*>(
                &Z[(size_t)(m0 + row) * 1024 + kbase + acol8 * 8]);
            *reinterpret_cast<short8*>(&As[row][acol8 * 8]) = a8;
        }
#pragma unroll
        for (int p = 0; p < 8; ++p) {
            const int row = lrow + p * 16;
            const float4 b4 = *reinterpret_cast<const float4*>(
                &Wo[(size_t)(n0 + row) * 1024 + kbase + lcol4 * 4]);
            ushort4v bv;
            bv[0] = f2bfu(b4.x); bv[1] = f2bfu(b4.y); bv[2] = f2bfu(b4.z); bv[3] = f2bfu(b4.w);
            *reinterpret_cast<ushort4v*>(&Bs[row][lcol4 * 4]) = bv;
        }
        __syncthreads();
#pragma unroll
        for (int ks = 0; ks < 2; ++ks) {
            short8 bf[4];
#pragma unroll
            for (int nt = 0; nt < 4; ++nt)
                bf[nt] = *reinterpret_cast<const short8*>(&Bs[wn * 64 + nt * 16 + c][ks * 32 + g * 8]);
#pragma unroll
            for (int mt = 0; mt < 4; ++mt) {
                const short8 af = *reinterpret_cast<const short8*>(&As[wm * 64 + mt * 16 + c][ks * 32 + g * 8]);
#pragma unroll
                for (int nt = 0; nt < 4; ++nt)
                    acc[mt][nt] = __builtin_amdgcn_mfma_f32_16x16x32_bf16(af, bf[nt], acc[mt][nt], 0, 0, 0);
            }
        }
        __syncthreads();
    }

#pragma unroll
    for (int nt = 0; nt < 4; ++nt) {
        const int n = n0 + wn * 64 + nt * 16 + c;
        const float bias = bo[n];
#pragma unroll
        for (int mt = 0; mt < 4; ++mt)
#pragma unroll
            for (int r = 0; r < 4; ++r) {
                const int m = m0 + wm * 64 + mt * 16 + g * 4 + r;
                out[(size_t)m * 1024 + n] = acc[mt][nt][r] + bias;
            }
    }
}

// ---------------------------------------------------------------------------
extern "C" void kernel_launch(void* const* d_in, const int* in_sizes, int n_in,
                              void* d_out, int out_size, void* d_ws, size_t ws_size,
                              hipStream_t stream) {
    const float* X  = (const float*)d_in[0];
    const float* Wq = (const float*)d_in[1];
    const float* Wk = (const float*)d_in[2];
    const float* Wv = (const float*)d_in[3];
    const float* Wo = (const float*)d_in[4];
    const float* bo = (const float*)d_in[5];
    float* out = (float*)d_out;

    const size_t elems = (size_t)Bq * Hq * Sq * DHq;  // 8,388,608
    unsigned short* q  = (unsigned short*)d_ws;
    unsigned short* k  = q + elems;
    unsigned short* vt = k + elems;
    unsigned short* o  = vt + elems;

    dim3 gq((Bq * Sq) / 128, Dq / 128, 2);
    qkv_gemm<false><<<gq, 256, 0, stream>>>(X, Wq, Wk, q, k);
    dim3 gv((Bq * Sq) / 128, Dq / 128, 1);
    qkv_gemm<true><<<gv, 256, 0, stream>>>(X, Wv, Wv, vt, vt);

    attn<<<dim3(1024), 256, 0, stream>>>(q, k, vt, o);

    dim3 gp((Bq * Sq) / 128, Dq / 128, 1);
    proj_gemm<<<gp, 256, 0, stream>>>(o, Wo, bo, out);
}